// Round 8
// baseline (5009.011 us; speedup 1.0000x reference)
//
#include <hip/hip_runtime.h>
#include <hip/hip_bf16.h>
#include <hip/hip_fp16.h>
#include <math.h>

constexpr int B = 32, S = 64, T = 64, H = 512, V = 32000;
constexpr int G3 = 3 * H;     // 1536
constexpr int BT = B * T;     // 2048

// ---- workspace layout (float slots) ----
constexpr size_t UAK_OFF    = 0;          // f32 [B*S][512]      1,048,576
constexpr size_t GIE_OFF    = 1048576;    // f32 [B*T][1536]     3,145,728 -> 4,194,304
constexpr size_t KWT2_OFF   = 4194304;    // u32 [B][1536][32]   1,572,864 -> 5,767,168
constexpr size_t WA2_OFF    = 5767168;    // u32 [512][256]        131,072 -> 5,898,240
constexpr size_t WHH2_OFF   = 5898240;    // u32 [1536][256]       393,216 -> 6,291,456
constexpr size_t ROWIDX_OFF = 6291456;    // 2048 ints             -> 6,293,504
constexpr size_t OWBF_OFF   = 0;          // bf16 [V*H] = 8,192,000 slots; aliases ALL of
                                          // the above (dead after k_recur)
constexpr size_t HBF_OFF    = 8192000;    // bf16 [B*T][512] = 524,288 slots -> 8,716,288

typedef __attribute__((ext_vector_type(8))) short bf16x8;
typedef __attribute__((ext_vector_type(4))) float f32x4;
typedef _Float16 h2v __attribute__((ext_vector_type(2)));

__device__ __forceinline__ float fast_tanh(float x) {
  float ax = fabsf(x);
  float e = __expf(-2.f * ax);
  float r = (1.f - e) / (1.f + e);
  return x < 0.f ? -r : r;
}
__device__ __forceinline__ float fast_sig(float x) {
  return 1.f / (1.f + __expf(-x));
}
__device__ __forceinline__ unsigned pack_h2(float a, float b) {
  __half2 h = __floats2half2_rn(a, b);
  return *(unsigned*)&h;
}
__device__ __forceinline__ float dot2acc(unsigned w, unsigned h, float c) {
  return __builtin_amdgcn_fdot2(__builtin_bit_cast(h2v, w),
                                __builtin_bit_cast(h2v, h), c, false);
}

// -------------------- init: token row indices --------------------
__global__ void k_init(const int* __restrict__ tgt, int* __restrict__ rowidx) {
  int i = blockIdx.x * 256 + threadIdx.x;      // grid 8*256 = 2048
  if (i < BT) {
    int b = i / T, t = i % T;
    rowidx[i] = (t == 0) ? 0 : tgt[b * T + t - 1];
  }
}

// -------------------- f32 [R][512] -> packed f16x2 [R][256] --------------------
__global__ void k_pack_h2(const float* __restrict__ in, unsigned* __restrict__ out, int n2) {
  int i = blockIdx.x * 256 + threadIdx.x;
  if (i < n2) {
    float2 v = *(const float2*)&in[2 * i];
    out[i] = pack_h2(v.x, v.y);
  }
}

// -------------------- out_w fp32 -> bf16 (runs AFTER recurrence; aliases ws) ----
__global__ void k_conv_outw(const float* __restrict__ w, ushort* __restrict__ o, int n4) {
  int i = blockIdx.x * blockDim.x + threadIdx.x;
  if (i < n4) {
    float4 v = *(const float4*)&w[(size_t)i * 4];
    ushort4 u;
    __hip_bfloat16 h0 = __float2bfloat16(v.x); u.x = *(ushort*)&h0;
    __hip_bfloat16 h1 = __float2bfloat16(v.y); u.y = *(ushort*)&h1;
    __hip_bfloat16 h2 = __float2bfloat16(v.z); u.z = *(ushort*)&h2;
    __hip_bfloat16 h3 = __float2bfloat16(v.w); u.w = *(ushort*)&h3;
    *(ushort4*)&o[(size_t)i * 4] = u;
  }
}

// -------- fp32 tiled GEMM, k-major LDS: C[m*N+n] = A[arow(m),:] . Bw[n,:] + bias[n] --------
__global__ __launch_bounds__(256) void k_gemm_at(
    const float* __restrict__ A, const float* __restrict__ Bw, int ldb,
    const float* __restrict__ bias, float* __restrict__ C,
    const int* __restrict__ rowidx, int N) {
  __shared__ float AsT[32][72];
  __shared__ float BsT[32][72];
  int tid = threadIdx.x;
  int bm = blockIdx.x, bn = blockIdx.y;
  int tr = tid >> 4, tc = tid & 15;
  float acc[4][4] = {};
  for (int k0 = 0; k0 < 512; k0 += 32) {
    __syncthreads();
#pragma unroll
    for (int i = 0; i < 2; i++) {
      int e = tid + i * 256;
      int row = e >> 3, c4 = (e & 7) * 4;
      int ar = bm * 64 + row;
      int arow = rowidx ? rowidx[ar] : ar;
      float4 v = *(const float4*)&A[(size_t)arow * 512 + k0 + c4];
      AsT[c4 + 0][row] = v.x; AsT[c4 + 1][row] = v.y;
      AsT[c4 + 2][row] = v.z; AsT[c4 + 3][row] = v.w;
      float4 u = *(const float4*)&Bw[(size_t)(bn * 64 + row) * ldb + k0 + c4];
      BsT[c4 + 0][row] = u.x; BsT[c4 + 1][row] = u.y;
      BsT[c4 + 2][row] = u.z; BsT[c4 + 3][row] = u.w;
    }
    __syncthreads();
#pragma unroll
    for (int kk = 0; kk < 32; kk++) {
      float4 a4 = *(const float4*)&AsT[kk][tr * 4];
      float4 b4 = *(const float4*)&BsT[kk][tc * 4];
      acc[0][0] += a4.x * b4.x; acc[0][1] += a4.x * b4.y; acc[0][2] += a4.x * b4.z; acc[0][3] += a4.x * b4.w;
      acc[1][0] += a4.y * b4.x; acc[1][1] += a4.y * b4.y; acc[1][2] += a4.y * b4.z; acc[1][3] += a4.y * b4.w;
      acc[2][0] += a4.z * b4.x; acc[2][1] += a4.z * b4.y; acc[2][2] += a4.z * b4.z; acc[2][3] += a4.z * b4.w;
      acc[3][0] += a4.w * b4.x; acc[3][1] += a4.w * b4.y; acc[3][2] += a4.w * b4.z; acc[3][3] += a4.w * b4.w;
    }
  }
#pragma unroll
  for (int i = 0; i < 4; i++) {
    int m = bm * 64 + tr * 4 + i;
#pragma unroll
    for (int j = 0; j < 4; j++) {
      int n = bn * 64 + tc * 4 + j;
      C[(size_t)m * N + n] = acc[i][j] + bias[n];
    }
  }
}

// -------- KWT2[b][col][s/2] (f16x2 packed) = W_ih[col, 512+k] . keys[b,s,k] --------
__global__ __launch_bounds__(256) void k_gemm_kwt(
    const float* __restrict__ W_ih, const float* __restrict__ keys,
    unsigned* __restrict__ KWT2) {
  __shared__ float AsT[32][72];
  __shared__ float BsT[32][72];
  int tid = threadIdx.x;
  int bm = blockIdx.x, b = blockIdx.y;
  int tr = tid >> 4, tc = tid & 15;
  float acc[4][4] = {};
  for (int k0 = 0; k0 < 512; k0 += 32) {
    __syncthreads();
#pragma unroll
    for (int i = 0; i < 2; i++) {
      int e = tid + i * 256;
      int row = e >> 3, c4 = (e & 7) * 4;
      float4 v = *(const float4*)&W_ih[(size_t)(bm * 64 + row) * 1024 + 512 + k0 + c4];
      AsT[c4 + 0][row] = v.x; AsT[c4 + 1][row] = v.y;
      AsT[c4 + 2][row] = v.z; AsT[c4 + 3][row] = v.w;
      float4 u = *(const float4*)&keys[(size_t)(b * 64 + row) * 512 + k0 + c4];
      BsT[c4 + 0][row] = u.x; BsT[c4 + 1][row] = u.y;
      BsT[c4 + 2][row] = u.z; BsT[c4 + 3][row] = u.w;
    }
    __syncthreads();
#pragma unroll
    for (int kk = 0; kk < 32; kk++) {
      float4 a4 = *(const float4*)&AsT[kk][tr * 4];
      float4 b4 = *(const float4*)&BsT[kk][tc * 4];
      acc[0][0] += a4.x * b4.x; acc[0][1] += a4.x * b4.y; acc[0][2] += a4.x * b4.z; acc[0][3] += a4.x * b4.w;
      acc[1][0] += a4.y * b4.x; acc[1][1] += a4.y * b4.y; acc[1][2] += a4.y * b4.z; acc[1][3] += a4.y * b4.w;
      acc[2][0] += a4.z * b4.x; acc[2][1] += a4.z * b4.y; acc[2][2] += a4.z * b4.z; acc[2][3] += a4.z * b4.w;
      acc[3][0] += a4.w * b4.x; acc[3][1] += a4.w * b4.y; acc[3][2] += a4.w * b4.z; acc[3][3] += a4.w * b4.w;
    }
  }
#pragma unroll
  for (int i = 0; i < 4; i++) {
    int m = bm * 64 + tr * 4 + i;   // col
    KWT2[((size_t)b * G3 + m) * 32 + tc * 2 + 0] = pack_h2(acc[i][0], acc[i][1]);
    KWT2[((size_t)b * G3 + m) * 32 + tc * 2 + 1] = pack_h2(acc[i][2], acc[i][3]);
  }
}

// -------------------- recurrence: ONE WG per batch, h LDS-resident, ZERO cross-WG sync ----
// grid 32 x 1024 threads. f16-packed weights via v_dot2_f32_f16 (2 MAC/instr, f32 accum).
// Per step: pack h -> q (512 dot, 2-way k-split) -> scores (64 s x 16 j-chunks,
// broadcast LDS reads) -> wave-0 softmax -> 1536 gate cols (gh + gic + GIE) -> GRU.
__global__ __launch_bounds__(1024, 1) void k_recur(
    const float* __restrict__ ehid,
    const float* __restrict__ Wa_b, const float* __restrict__ Va_w,
    const float* __restrict__ Va_b, const float* __restrict__ b_hh,
    const unsigned* __restrict__ WA2, const unsigned* __restrict__ WHH2,
    const unsigned* __restrict__ KWT2, const float* __restrict__ UAK,
    const float* __restrict__ GIE, __hip_bfloat16* __restrict__ HBF,
    float* __restrict__ attn_out, float* __restrict__ ht_out) {
  const int b = blockIdx.x;
  const int tid = threadIdx.x;
  __shared__ float sh[512];
  __shared__ unsigned sH2[256];
  __shared__ float spq[2][520];
  __shared__ float sq[512];
  __shared__ float sVa[512];
  __shared__ float spp[64][17];
  __shared__ unsigned sW2[32];
  __shared__ float sR[512], sZ[512], sNi[512], sNh[512];

  if (tid < 512) { sh[tid] = ehid[b * H + tid]; sVa[tid] = Va_w[tid]; }
  __syncthreads();

  for (int t = 0; t < T; ++t) {
    // P0: pack h to f16 pairs
    if (tid < 256) sH2[tid] = pack_h2(sh[2 * tid], sh[2 * tid + 1]);
    __syncthreads();
    // P1: q[j] partials (j = tid>>1, k-half = tid&1)
    {
      int j = tid >> 1, kh = tid & 1;
      const unsigned* wr = WA2 + j * 256 + kh * 128;
      float a0 = 0, a1 = 0, a2 = 0, a3 = 0;
#pragma unroll 8
      for (int i = 0; i < 128; i += 4) {
        uint4 wv = *(const uint4*)&wr[i];
        int kk = kh * 128 + i;
        a0 = dot2acc(wv.x, sH2[kk], a0);
        a1 = dot2acc(wv.y, sH2[kk + 1], a1);
        a2 = dot2acc(wv.z, sH2[kk + 2], a2);
        a3 = dot2acc(wv.w, sH2[kk + 3], a3);
      }
      spq[kh][j] = (a0 + a1) + (a2 + a3);
    }
    __syncthreads();
    if (tid < 512) sq[tid] = spq[0][tid] + spq[1][tid] + Wa_b[tid];
    __syncthreads();
    // P3: score partials: jc = tid>>6 (16 chunks of 32 j), s = tid&63
    // (sq/sVa reads are wave-uniform -> LDS broadcast, conflict-free)
    {
      int jc = tid >> 6, s = tid & 63;
      const float* ur = UAK + ((size_t)(b * 64 + s)) * 512 + jc * 32;
      const float* qq = sq + jc * 32;
      const float* vv = sVa + jc * 32;
      float a0 = 0.f, a1 = 0.f;
#pragma unroll
      for (int i = 0; i < 32; i += 4) {
        float4 u4 = *(const float4*)&ur[i];
        a0 += vv[i] * fast_tanh(qq[i] + u4.x);
        a1 += vv[i + 1] * fast_tanh(qq[i + 1] + u4.y);
        a0 += vv[i + 2] * fast_tanh(qq[i + 2] + u4.z);
        a1 += vv[i + 3] * fast_tanh(qq[i + 3] + u4.w);
      }
      spp[s][jc] = a0 + a1;
    }
    __syncthreads();
    // P4: softmax on wave 0
    if (tid < 64) {
      float v = Va_b[0];
#pragma unroll
      for (int i = 0; i < 16; i++) v += spp[tid][i];
      float m = v;
      for (int o = 32; o; o >>= 1) m = fmaxf(m, __shfl_xor(m, o, 64));
      float e = __expf(v - m);
      float su = e;
      for (int o = 32; o; o >>= 1) su += __shfl_xor(su, o, 64);
      float wt = e / su;
      attn_out[((size_t)b * T + t) * S + tid] = wt;
      float w0 = __shfl(wt, 2 * (tid & 31), 64);
      float w1 = __shfl(wt, 2 * (tid & 31) + 1, 64);
      if (tid < 32) sW2[tid] = pack_h2(w0, w1);
    }
    __syncthreads();
    // P5: gate cols (1536): gh = Whh.h, gic = KWT.wt, gi = GIE + gic
    for (int col = tid; col < G3; col += 1024) {
      const unsigned* wr = WHH2 + (size_t)col * 256;
      float g0 = 0, g1 = 0, g2 = 0, g3 = 0;
#pragma unroll 8
      for (int kk = 0; kk < 256; kk += 4) {
        uint4 wv = *(const uint4*)&wr[kk];
        g0 = dot2acc(wv.x, sH2[kk], g0);
        g1 = dot2acc(wv.y, sH2[kk + 1], g1);
        g2 = dot2acc(wv.z, sH2[kk + 2], g2);
        g3 = dot2acc(wv.w, sH2[kk + 3], g3);
      }
      float gh = (g0 + g1) + (g2 + g3) + b_hh[col];
      const unsigned* kw = KWT2 + ((size_t)b * G3 + col) * 32;
      float c0 = 0, c1 = 0;
#pragma unroll
      for (int ss = 0; ss < 32; ss += 4) {
        uint4 kv = *(const uint4*)&kw[ss];
        c0 = dot2acc(kv.x, sW2[ss], c0);
        c1 = dot2acc(kv.y, sW2[ss + 1], c1);
        c0 = dot2acc(kv.z, sW2[ss + 2], c0);
        c1 = dot2acc(kv.w, sW2[ss + 3], c1);
      }
      float gi = GIE[((size_t)b * T + t) * G3 + col] + c0 + c1;
      if (col < 512) sR[col] = gi + gh;
      else if (col < 1024) sZ[col - 512] = gi + gh;
      else { sNi[col - 1024] = gi; sNh[col - 1024] = gh; }
    }
    __syncthreads();
    // P6: GRU update (h stays in LDS)
    if (tid < 512) {
      float r = fast_sig(sR[tid]);
      float z = fast_sig(sZ[tid]);
      float n = fast_tanh(sNi[tid] + r * sNh[tid]);
      float hn = (1.f - z) * n + z * sh[tid];
      sh[tid] = hn;
      HBF[((size_t)b * T + t) * 512 + tid] = __float2bfloat16(hn);
    }
    __syncthreads();
  }
  if (tid < 512) ht_out[b * 512 + tid] = sh[tid];
}

// -------------------- bf16 MFMA out-projection: [2048,512] x [32000,512]^T --------------------
__global__ __launch_bounds__(256) void k_outgemm(
    const __hip_bfloat16* __restrict__ Abf, const __hip_bfloat16* __restrict__ Bbf,
    const float* __restrict__ bias, float* __restrict__ Cmat) {
  constexpr int LDT = 40;
  __shared__ __align__(16) short As[128 * LDT];
  __shared__ __align__(16) short Bs[128 * LDT];
  int bm = blockIdx.y, bn = blockIdx.x;
  int tid = threadIdx.x;
  int lane = tid & 63, wid = tid >> 6;
  int wm = wid >> 1, wn = wid & 1;
  f32x4 acc[4][4] = {};
  int srow = tid >> 1, shalf = tid & 1;
  for (int k0 = 0; k0 < 512; k0 += 32) {
    const float4* ga = (const float4*)&Abf[(size_t)(bm * 128 + srow) * 512 + k0 + shalf * 16];
    const float4* gb = (const float4*)&Bbf[(size_t)(bn * 128 + srow) * 512 + k0 + shalf * 16];
    float4 va0 = ga[0], va1 = ga[1];
    float4 vb0 = gb[0], vb1 = gb[1];
    __syncthreads();
    *(float4*)&As[srow * LDT + shalf * 16] = va0;
    *(float4*)&As[srow * LDT + shalf * 16 + 8] = va1;
    *(float4*)&Bs[srow * LDT + shalf * 16] = vb0;
    *(float4*)&Bs[srow * LDT + shalf * 16 + 8] = vb1;
    __syncthreads();
    int kc = lane >> 4, rl = lane & 15;
    bf16x8 af[4], bfv[4];
#pragma unroll
    for (int f = 0; f < 4; f++) {
      af[f] = *(const bf16x8*)&As[(wm * 64 + f * 16 + rl) * LDT + kc * 8];
      bfv[f] = *(const bf16x8*)&Bs[(wn * 64 + f * 16 + rl) * LDT + kc * 8];
    }
#pragma unroll
    for (int i = 0; i < 4; i++)
#pragma unroll
      for (int j = 0; j < 4; j++)
        acc[i][j] = __builtin_amdgcn_mfma_f32_16x16x32_bf16(af[i], bfv[j], acc[i][j], 0, 0, 0);
  }
  int cl = lane & 15, rg = lane >> 4;
#pragma unroll
  for (int i = 0; i < 4; i++) {
    int m = bm * 128 + wm * 64 + i * 16 + rg * 4;
#pragma unroll
    for (int j = 0; j < 4; j++) {
      int n = bn * 128 + wn * 64 + j * 16 + cl;
      float bv = bias[n];
#pragma unroll
      for (int r = 0; r < 4; r++)
        Cmat[(size_t)(m + r) * V + n] = acc[i][j][r] + bv;
    }
  }
}

// -------------------- in-place log_softmax (online stats, 2 passes) --------------------
__global__ __launch_bounds__(256) void k_logsoftmax(float* __restrict__ Cmat) {
  int row = blockIdx.x;
  float* p = Cmat + (size_t)row * V;
  int tid = threadIdx.x;
  __shared__ float sm[4], ss[4];
  float m = -1e30f, s = 0.f;
  for (int i = tid * 4; i < V; i += 1024) {
    float4 v = *(const float4*)&p[i];
    float m4 = fmaxf(fmaxf(v.x, v.y), fmaxf(v.z, v.w));
    float nm = fmaxf(m, m4);
    s = s * __expf(m - nm) + __expf(v.x - nm) + __expf(v.y - nm)
      + __expf(v.z - nm) + __expf(v.w - nm);
    m = nm;
  }
  for (int o = 32; o; o >>= 1) {
    float om = __shfl_xor(m, o, 64), os = __shfl_xor(s, o, 64);
    float nm = fmaxf(m, om);
    s = s * __expf(m - nm) + os * __expf(om - nm);
    m = nm;
  }
  if ((tid & 63) == 0) { sm[tid >> 6] = m; ss[tid >> 6] = s; }
  __syncthreads();
  float M = fmaxf(fmaxf(sm[0], sm[1]), fmaxf(sm[2], sm[3]));
  float Ssum = ss[0] * __expf(sm[0] - M) + ss[1] * __expf(sm[1] - M)
             + ss[2] * __expf(sm[2] - M) + ss[3] * __expf(sm[3] - M);
  float lse = M + __logf(Ssum);
  for (int i = tid * 4; i < V; i += 1024) {
    float4 v = *(const float4*)&p[i];
    v.x -= lse; v.y -= lse; v.z -= lse; v.w -= lse;
    *(float4*)&p[i] = v;
  }
}

extern "C" void kernel_launch(void* const* d_in, const int* in_sizes, int n_in,
                              void* d_out, int out_size, void* d_ws, size_t ws_size,
                              hipStream_t stream) {
  (void)in_sizes; (void)n_in; (void)out_size; (void)ws_size;
  const float* keys = (const float*)d_in[0];
  const float* ehid = (const float*)d_in[1];
  const int* tgt    = (const int*)d_in[2];
  const float* emb  = (const float*)d_in[4];
  const float* Wa_w = (const float*)d_in[5];
  const float* Wa_b = (const float*)d_in[6];
  const float* Ua_w = (const float*)d_in[7];
  const float* Ua_b = (const float*)d_in[8];
  const float* Va_w = (const float*)d_in[9];
  const float* Va_b = (const float*)d_in[10];
  const float* W_ih = (const float*)d_in[11];
  const float* W_hh = (const float*)d_in[12];
  const float* b_ih = (const float*)d_in[13];
  const float* b_hh = (const float*)d_in[14];
  const float* out_w = (const float*)d_in[15];
  const float* out_b = (const float*)d_in[16];
  float* ws = (float*)d_ws;
  float* out = (float*)d_out;
  float* logits = out;                              // [B,T,V]
  float* ht_out = out + (size_t)B * T * V;          // [1,B,H]
  float* attn_out = ht_out + (size_t)B * H;         // [B,T,S]

  hipLaunchKernelGGL(k_init, dim3(8), dim3(256), 0, stream,
                     tgt, (int*)(ws + ROWIDX_OFF));
  // Ua_keys = keys @ Ua_w.T + Ua_b -> [B*S][512]
  hipLaunchKernelGGL(k_gemm_at, dim3(32, 8), dim3(256), 0, stream,
                     keys, Ua_w, 512, Ua_b, ws + UAK_OFF, (const int*)nullptr, 512);
  // Gi_e = emb[tokens] @ W_ih[:, :512].T + b_ih -> [B*T][1536]
  hipLaunchKernelGGL(k_gemm_at, dim3(32, 24), dim3(256), 0, stream,
                     emb, W_ih, 1024, b_ih, ws + GIE_OFF, (const int*)(ws + ROWIDX_OFF), G3);
  // KWT2 packed f16x2
  hipLaunchKernelGGL(k_gemm_kwt, dim3(24, 32), dim3(256), 0, stream,
                     W_ih, keys, (unsigned*)(ws + KWT2_OFF));
  // pack Wa, W_hh to f16x2
  hipLaunchKernelGGL(k_pack_h2, dim3(512), dim3(256), 0, stream,
                     Wa_w, (unsigned*)(ws + WA2_OFF), 512 * 256);
  hipLaunchKernelGGL(k_pack_h2, dim3(1536), dim3(256), 0, stream,
                     W_hh, (unsigned*)(ws + WHH2_OFF), 1536 * 256);
  // recurrence: one WG per batch, zero cross-WG sync
  hipLaunchKernelGGL(k_recur, dim3(32), dim3(1024), 0, stream,
                     ehid, Wa_b, Va_w, Va_b, b_hh,
                     (const unsigned*)(ws + WA2_OFF), (const unsigned*)(ws + WHH2_OFF),
                     (const unsigned*)(ws + KWT2_OFF), ws + UAK_OFF, ws + GIE_OFF,
                     (__hip_bfloat16*)(ws + HBF_OFF), attn_out, ht_out);
  // bf16 out_w copy into the (now dead) precompute region
  hipLaunchKernelGGL(k_conv_outw, dim3((V * H / 4 + 255) / 256), dim3(256), 0, stream,
                     out_w, (ushort*)(ws + OWBF_OFF), V * H / 4);
  hipLaunchKernelGGL(k_outgemm, dim3(250, 16), dim3(256), 0, stream,
                     (const __hip_bfloat16*)(ws + HBF_OFF),
                     (const __hip_bfloat16*)(ws + OWBF_OFF), out_b, logits);
  hipLaunchKernelGGL(k_logsoftmax, dim3(BT), dim3(256), 0, stream, logits);
}

// Round 9
// 1443.074 us; speedup vs baseline: 3.4711x; 3.4711x over previous
//
#include <hip/hip_runtime.h>
#include <hip/hip_bf16.h>
#include <hip/hip_fp16.h>
#include <math.h>

constexpr int B = 32, S = 64, T = 64, H = 512, V = 32000;
constexpr int G3 = 3 * H;     // 1536
constexpr int BT = B * T;     // 2048

// ---- workspace layout (float slots) ----
constexpr size_t UAK_OFF    = 0;          // f32 [B*S][512]     1,048,576
constexpr size_t GIE_OFF    = 1048576;    // f32 [B*T][1536]    3,145,728 -> 4,194,304
constexpr size_t KWT_OFF    = 4194304;    // f32 [B][G3][64]    3,145,728 -> 7,340,032
constexpr size_t WA2T_OFF   = 7340032;    // u32 [256][512]       131,072 -> 7,471,104
constexpr size_t WHH2T_OFF  = 7471104;    // u32 [256][1536]      393,216 -> 7,864,320
constexpr size_t ROWIDX_OFF = 7864320;    // 2048 ints            -> 7,866,368
constexpr size_t SCP_OFF    = 7866368;    // f32 [B][8][64]        16,384 -> 7,882,752
constexpr size_t FLG_OFF    = 7882752;    // T*64 ints              4,096 -> 7,886,848
constexpr size_t OWBF_OFF   = 0;          // bf16 [V*H] = 8,192,000 slots; aliases all
                                          // of the above (dead after k_recur)
constexpr size_t HALL_OFF   = 8192000;    // f32 [(T+1)*B*H]    1,064,960 -> 9,256,960
constexpr size_t HBF_OFF    = 9256960;    // bf16 [B*T*H] 524,288 slots  -> 9,781,248

typedef __attribute__((ext_vector_type(8))) short bf16x8;
typedef __attribute__((ext_vector_type(4))) float f32x4;
typedef _Float16 h2v __attribute__((ext_vector_type(2)));

__device__ __forceinline__ float fast_tanh(float x) {
  float ax = fabsf(x);
  float e = __expf(-2.f * ax);
  float r = (1.f - e) / (1.f + e);
  return x < 0.f ? -r : r;
}
__device__ __forceinline__ float fast_sig(float x) {
  return 1.f / (1.f + __expf(-x));
}
__device__ __forceinline__ unsigned pack_h2(float a, float b) {
  __half2 h = __floats2half2_rn(a, b);
  return *(unsigned*)&h;
}
__device__ __forceinline__ float dot2acc(unsigned w, unsigned h, float c) {
  return __builtin_amdgcn_fdot2(__builtin_bit_cast(h2v, w),
                                __builtin_bit_cast(h2v, h), c, false);
}
__device__ __forceinline__ int load_coh_i32(const int* p) {
  int v;
  asm volatile("global_load_dword %0, %1, off sc0 sc1\n\ts_waitcnt vmcnt(0)"
               : "=v"(v) : "v"(p) : "memory");
  return v;
}
__device__ __forceinline__ f32x4 load_coh_f32x4(const float* p) {
  f32x4 v;
  asm volatile("global_load_dwordx4 %0, %1, off sc0 sc1\n\ts_waitcnt vmcnt(0)"
               : "=v"(v) : "v"(p) : "memory");
  return v;
}
__device__ __forceinline__ void store_coh_f32x4(float* p, f32x4 v) {
  asm volatile("global_store_dwordx4 %0, %1, off sc0 sc1" :: "v"(p), "v"(v) : "memory");
}

// -------------------- init: h0, token row indices, flags --------------------
__global__ void k_init(const float* __restrict__ eh, const int* __restrict__ tgt,
                       float* __restrict__ ws) {
  int i = blockIdx.x * 256 + threadIdx.x;      // grid 64*256 = 16384
  if (i < B * H) ws[HALL_OFF + i] = eh[i];
  if (i < BT) {
    int b = i / T, t = i % T;
    ((int*)(ws + ROWIDX_OFF))[i] = (t == 0) ? 0 : tgt[b * T + t - 1];
  }
  if (i < T * 64) ((int*)(ws + FLG_OFF))[i] = 0;
}

// -------------------- f32 [R][512] -> k-major packed f16x2 [256][R] --------------------
__global__ void k_pack_t(const float* __restrict__ in, unsigned* __restrict__ out, int R) {
  int i = blockIdx.x * 256 + threadIdx.x;
  if (i < R * 256) {
    int r = i >> 8, kk = i & 255;
    float2 v = *(const float2*)&in[(size_t)r * 512 + 2 * kk];
    out[(size_t)kk * R + r] = pack_h2(v.x, v.y);
  }
}

// -------------------- out_w fp32 -> bf16 (runs AFTER recurrence; aliases ws) ----
__global__ void k_conv_outw(const float* __restrict__ w, ushort* __restrict__ o, int n4) {
  int i = blockIdx.x * blockDim.x + threadIdx.x;
  if (i < n4) {
    float4 v = *(const float4*)&w[(size_t)i * 4];
    ushort4 u;
    __hip_bfloat16 h0 = __float2bfloat16(v.x); u.x = *(ushort*)&h0;
    __hip_bfloat16 h1 = __float2bfloat16(v.y); u.y = *(ushort*)&h1;
    __hip_bfloat16 h2 = __float2bfloat16(v.z); u.z = *(ushort*)&h2;
    __hip_bfloat16 h3 = __float2bfloat16(v.w); u.w = *(ushort*)&h3;
    *(ushort4*)&o[(size_t)i * 4] = u;
  }
}

// -------- fp32 tiled GEMM, k-major LDS: C[m*N+n] = A[arow(m),:] . Bw[n,:] + bias[n] --------
__global__ __launch_bounds__(256) void k_gemm_at(
    const float* __restrict__ A, const float* __restrict__ Bw, int ldb,
    const float* __restrict__ bias, float* __restrict__ C,
    const int* __restrict__ rowidx, int N) {
  __shared__ float AsT[32][72];
  __shared__ float BsT[32][72];
  int tid = threadIdx.x;
  int bm = blockIdx.x, bn = blockIdx.y;
  int tr = tid >> 4, tc = tid & 15;
  float acc[4][4] = {};
  for (int k0 = 0; k0 < 512; k0 += 32) {
    __syncthreads();
#pragma unroll
    for (int i = 0; i < 2; i++) {
      int e = tid + i * 256;
      int row = e >> 3, c4 = (e & 7) * 4;
      int ar = bm * 64 + row;
      int arow = rowidx ? rowidx[ar] : ar;
      float4 v = *(const float4*)&A[(size_t)arow * 512 + k0 + c4];
      AsT[c4 + 0][row] = v.x; AsT[c4 + 1][row] = v.y;
      AsT[c4 + 2][row] = v.z; AsT[c4 + 3][row] = v.w;
      float4 u = *(const float4*)&Bw[(size_t)(bn * 64 + row) * ldb + k0 + c4];
      BsT[c4 + 0][row] = u.x; BsT[c4 + 1][row] = u.y;
      BsT[c4 + 2][row] = u.z; BsT[c4 + 3][row] = u.w;
    }
    __syncthreads();
#pragma unroll
    for (int kk = 0; kk < 32; kk++) {
      float4 a4 = *(const float4*)&AsT[kk][tr * 4];
      float4 b4 = *(const float4*)&BsT[kk][tc * 4];
      acc[0][0] += a4.x * b4.x; acc[0][1] += a4.x * b4.y; acc[0][2] += a4.x * b4.z; acc[0][3] += a4.x * b4.w;
      acc[1][0] += a4.y * b4.x; acc[1][1] += a4.y * b4.y; acc[1][2] += a4.y * b4.z; acc[1][3] += a4.y * b4.w;
      acc[2][0] += a4.z * b4.x; acc[2][1] += a4.z * b4.y; acc[2][2] += a4.z * b4.z; acc[2][3] += a4.z * b4.w;
      acc[3][0] += a4.w * b4.x; acc[3][1] += a4.w * b4.y; acc[3][2] += a4.w * b4.z; acc[3][3] += a4.w * b4.w;
    }
  }
#pragma unroll
  for (int i = 0; i < 4; i++) {
    int m = bm * 64 + tr * 4 + i;
#pragma unroll
    for (int j = 0; j < 4; j++) {
      int n = bn * 64 + tc * 4 + j;
      C[(size_t)m * N + n] = acc[i][j] + bias[n];
    }
  }
}

// -------- KWT[b, col, s] = sum_k W_ih[col, 512+k] * keys[b*64+s, k]  (f32) --------
__global__ __launch_bounds__(256) void k_gemm_kwt(
    const float* __restrict__ W_ih, const float* __restrict__ keys,
    float* __restrict__ KWT) {
  __shared__ float AsT[32][72];
  __shared__ float BsT[32][72];
  int tid = threadIdx.x;
  int bm = blockIdx.x, b = blockIdx.y;
  int tr = tid >> 4, tc = tid & 15;
  float acc[4][4] = {};
  for (int k0 = 0; k0 < 512; k0 += 32) {
    __syncthreads();
#pragma unroll
    for (int i = 0; i < 2; i++) {
      int e = tid + i * 256;
      int row = e >> 3, c4 = (e & 7) * 4;
      float4 v = *(const float4*)&W_ih[(size_t)(bm * 64 + row) * 1024 + 512 + k0 + c4];
      AsT[c4 + 0][row] = v.x; AsT[c4 + 1][row] = v.y;
      AsT[c4 + 2][row] = v.z; AsT[c4 + 3][row] = v.w;
      float4 u = *(const float4*)&keys[(size_t)(b * 64 + row) * 512 + k0 + c4];
      BsT[c4 + 0][row] = u.x; BsT[c4 + 1][row] = u.y;
      BsT[c4 + 2][row] = u.z; BsT[c4 + 3][row] = u.w;
    }
    __syncthreads();
#pragma unroll
    for (int kk = 0; kk < 32; kk++) {
      float4 a4 = *(const float4*)&AsT[kk][tr * 4];
      float4 b4 = *(const float4*)&BsT[kk][tc * 4];
      acc[0][0] += a4.x * b4.x; acc[0][1] += a4.x * b4.y; acc[0][2] += a4.x * b4.z; acc[0][3] += a4.x * b4.w;
      acc[1][0] += a4.y * b4.x; acc[1][1] += a4.y * b4.y; acc[1][2] += a4.y * b4.z; acc[1][3] += a4.y * b4.w;
      acc[2][0] += a4.z * b4.x; acc[2][1] += a4.z * b4.y; acc[2][2] += a4.z * b4.z; acc[2][3] += a4.z * b4.w;
      acc[3][0] += a4.w * b4.x; acc[3][1] += a4.w * b4.y; acc[3][2] += a4.w * b4.z; acc[3][3] += a4.w * b4.w;
    }
  }
#pragma unroll
  for (int i = 0; i < 4; i++) {
    int m = bm * 64 + tr * 4 + i;
#pragma unroll
    for (int j = 0; j < 4; j++)
      KWT[((size_t)b * G3 + m) * 64 + tc * 4 + j] = acc[i][j];
  }
}

// -------------------- persistent recurrence v4: per-batch pipelines, coalesced f16 weights ----
// 256 WGs x 256 thr. WG w = (b=w>>3, cb=w&7): batch b, col slice [cb*64, +64).
// Weights k-major packed f16x2 -> q/gh reads coalesced (256B/wave-instr) via v_dot2.
// Per step: poll hflag(b,t-1)==8 -> stage h + prefetch GIE -> q-slice -> scores
// (f32 LDS UAK) -> SCP store + sflag -> gh (coalesced; overlaps peers) ->
// poll sflag==8 -> coherent SCP read + softmax -> gic (LDS KWT f32) -> GRU ->
// h store + hflag. 2 per-batch handshakes/step, no global barrier.
__global__ __launch_bounds__(256) void k_recur(
    const float* __restrict__ Wa_b, const float* __restrict__ Va_w,
    const float* __restrict__ Va_b, const float* __restrict__ b_hh,
    const unsigned* __restrict__ WA2T, const unsigned* __restrict__ WHH2T,
    float* __restrict__ ws, float* __restrict__ attn_out) {
  const int w = blockIdx.x;
  const int tid = threadIdx.x;
  const int b = w >> 3, cb = w & 7;
  const int j0 = cb * 64;
  int* flg = (int*)(ws + FLG_OFF);
  __hip_bfloat16* HBF = (__hip_bfloat16*)(ws + HBF_OFF);
  const float* GIE = ws + GIE_OFF;
  float* SCP = ws + SCP_OFF;

  __shared__ float sKWT[192][68];   // 52.2 KB (f32, 16B-aligned rows)
  __shared__ float sUAK[64][68];    // 17.4 KB
  __shared__ float sh[512];
  __shared__ unsigned sH2[256];
  __shared__ float sq[64];
  __shared__ float qp[64][5];
  __shared__ float spp[64][5];
  __shared__ float sps[64];
  __shared__ float scg[8][64];
  __shared__ float swt[64];
  __shared__ float sga[4][64];
  __shared__ float shn[64];
  __shared__ float sVa[64], sWab[64], sBhh[192];

  // ---- one-time staging ----
#pragma unroll
  for (int g = 0; g < 3; g++) {
    int jl = tid >> 2, part = tid & 3;
    const float* src = ws + KWT_OFF + ((size_t)b * G3 + g * 512 + j0 + jl) * 64 + part * 16;
    float* dst = &sKWT[g * 64 + jl][part * 16];
#pragma unroll
    for (int i = 0; i < 16; i += 4) *(float4*)&dst[i] = *(const float4*)&src[i];
  }
  {
    int s = tid >> 2, part = tid & 3;
    const float* src = ws + UAK_OFF + ((size_t)(b * 64 + s)) * 512 + j0 + part * 16;
    float* dst = &sUAK[s][part * 16];
#pragma unroll
    for (int i = 0; i < 16; i += 4) *(float4*)&dst[i] = *(const float4*)&src[i];
  }
  if (tid < 64) { sVa[tid] = Va_w[j0 + tid]; sWab[tid] = Wa_b[j0 + tid]; }
  if (tid < 192) sBhh[tid] = b_hh[(tid >> 6) * 512 + j0 + (tid & 63)];
  const float va_b = Va_b[0];
  __syncthreads();

  for (int t = 0; t < T; ++t) {
    // ---- wait for h_t ----
    if (t > 0) {
      if (tid == 0)
        while (load_coh_i32(&flg[(t - 1) * 64 + b * 2]) != 8) __builtin_amdgcn_s_sleep(1);
    }
    __syncthreads();
    const float* hcur = ws + HALL_OFF + (size_t)t * B * H + b * H;
    sh[tid] = hcur[tid];
    sh[tid + 256] = hcur[tid + 256];
    // prefetch GIE for this step (coalesced, consumed in combine phase)
    float gival = 0.f;
    if (tid < 192)
      gival = GIE[((size_t)b * T + t) * G3 + (tid >> 6) * 512 + j0 + (tid & 63)];
    __syncthreads();
    if (tid < 256) sH2[tid] = pack_h2(sh[2 * tid], sh[2 * tid + 1]);
    __syncthreads();

    // ---- q slice (coalesced k-major): jq = tid&63, kp = tid>>6 ----
    {
      int jq = tid & 63, kp = tid >> 6;
      const unsigned* wp = WA2T + (size_t)(kp * 64) * 512 + j0 + jq;
      float acc = 0.f;
#pragma unroll 8
      for (int kk = 0; kk < 64; kk++)
        acc = dot2acc(wp[(size_t)kk * 512], sH2[kp * 64 + kk], acc);
      qp[jq][kp] = acc;
    }
    __syncthreads();
    if (tid < 64)
      sq[tid] = qp[tid][0] + qp[tid][1] + qp[tid][2] + qp[tid][3] + sWab[tid];
    __syncthreads();
    // ---- score partials over this WG's 64-j slice (f32 LDS) ----
    {
      int s = tid >> 2, jc = tid & 3;
      float accs = 0.f;
#pragma unroll
      for (int i = 0; i < 16; i++) {
        int j = jc * 16 + i;
        accs += sVa[j] * fast_tanh(sq[j] + sUAK[s][j]);
      }
      spp[s][jc] = accs;
    }
    __syncthreads();
    if (tid < 64) {
      float v = spp[tid][0] + spp[tid][1] + spp[tid][2] + spp[tid][3];
      if (cb == 0) v += va_b;
      sps[tid] = v;
    }
    __syncthreads();
    if (tid < 16)
      store_coh_f32x4(SCP + ((size_t)b * 8 + cb) * 64 + tid * 4, *(f32x4*)&sps[tid * 4]);
    if (tid == 0) {
      asm volatile("s_waitcnt vmcnt(0)" ::: "memory");
      __hip_atomic_fetch_add(&flg[t * 64 + b * 2 + 1], 1,
                             __ATOMIC_RELAXED, __HIP_MEMORY_SCOPE_AGENT);
    }

    // ---- gh (coalesced k-major f16): 3 waves, col = gate*512 + j0 + lane ----
    float gh = 0.f;
    if (tid < 192) {
      int gate = tid >> 6, lane = tid & 63;
      const unsigned* wp = WHH2T + gate * 512 + j0 + lane;
      float g0 = 0.f, g1 = 0.f;
#pragma unroll 8
      for (int kk = 0; kk < 256; kk += 2) {
        g0 = dot2acc(wp[(size_t)kk * 1536], sH2[kk], g0);
        g1 = dot2acc(wp[(size_t)(kk + 1) * 1536], sH2[kk + 1], g1);
      }
      gh = g0 + g1 + sBhh[tid];
    }
    // ---- wait all 8 score slices of batch b ----
    if (tid == 0)
      while (load_coh_i32(&flg[t * 64 + b * 2 + 1]) != 8) __builtin_amdgcn_s_sleep(1);
    __syncthreads();
    // ---- coherent SCP read + reduce + softmax ----
    if (tid < 128) {
      f32x4 v = load_coh_f32x4(SCP + (size_t)b * 512 + tid * 4);
      *(f32x4*)&scg[tid >> 4][(tid & 15) * 4] = v;
    }
    __syncthreads();
    if (tid < 64) {
      float v = scg[0][tid] + scg[1][tid] + scg[2][tid] + scg[3][tid]
              + scg[4][tid] + scg[5][tid] + scg[6][tid] + scg[7][tid];
      float m = v;
      for (int o = 32; o; o >>= 1) m = fmaxf(m, __shfl_xor(m, o, 64));
      float e = __expf(v - m);
      float su = e;
      for (int o = 32; o; o >>= 1) su += __shfl_xor(su, o, 64);
      float wt = e / su;
      swt[tid] = wt;
      if (cb == 0) attn_out[((size_t)b * T + t) * S + tid] = wt;
    }
    __syncthreads();
    // ---- gic = KWT . wt (LDS f32) ; combine with prefetched GIE + gh ----
    if (tid < 192) {
      int gate = tid >> 6, lane = tid & 63;
      float gic = 0.f;
#pragma unroll
      for (int s4 = 0; s4 < 64; s4 += 4) {
        float4 k4 = *(const float4*)&sKWT[tid][s4];
        gic += k4.x * swt[s4] + k4.y * swt[s4 + 1] + k4.z * swt[s4 + 2] + k4.w * swt[s4 + 3];
      }
      float gi = gival + gic;
      if (gate == 0) sga[0][lane] = gi + gh;
      else if (gate == 1) sga[1][lane] = gi + gh;
      else { sga[2][lane] = gi; sga[3][lane] = gh; }
    }
    __syncthreads();
    // ---- GRU update for the 64 owned h-cols ----
    if (tid < 64) {
      float r = fast_sig(sga[0][tid]);
      float z = fast_sig(sga[1][tid]);
      float n = fast_tanh(sga[2][tid] + r * sga[3][tid]);
      float hold = sh[j0 + tid];
      float hn = (1.f - z) * n + z * hold;
      shn[tid] = hn;
      HBF[((size_t)b * T + t) * H + j0 + tid] = __float2bfloat16(hn);
    }
    __syncthreads();
    if (tid < 16)
      store_coh_f32x4(ws + HALL_OFF + (size_t)(t + 1) * B * H + b * H + j0 + tid * 4,
                      *(f32x4*)&shn[tid * 4]);
    if (tid == 0) {
      asm volatile("s_waitcnt vmcnt(0)" ::: "memory");
      __hip_atomic_fetch_add(&flg[t * 64 + b * 2], 1,
                             __ATOMIC_RELAXED, __HIP_MEMORY_SCOPE_AGENT);
    }
  }
}

// -------------------- bf16 MFMA out-projection: [2048,512] x [32000,512]^T --------------------
__global__ __launch_bounds__(256) void k_outgemm(
    const __hip_bfloat16* __restrict__ Abf, const __hip_bfloat16* __restrict__ Bbf,
    const float* __restrict__ bias, float* __restrict__ Cmat) {
  constexpr int LDT = 40;
  __shared__ __align__(16) short As[128 * LDT];
  __shared__ __align__(16) short Bs[128 * LDT];
  int bm = blockIdx.y, bn = blockIdx.x;
  int tid = threadIdx.x;
  int lane = tid & 63, wid = tid >> 6;
  int wm = wid >> 1, wn = wid & 1;
  f32x4 acc[4][4] = {};
  int srow = tid >> 1, shalf = tid & 1;
  for (int k0 = 0; k0 < 512; k0 += 32) {
    const float4* ga = (const float4*)&Abf[(size_t)(bm * 128 + srow) * 512 + k0 + shalf * 16];
    const float4* gb = (const float4*)&Bbf[(size_t)(bn * 128 + srow) * 512 + k0 + shalf * 16];
    float4 va0 = ga[0], va1 = ga[1];
    float4 vb0 = gb[0], vb1 = gb[1];
    __syncthreads();
    *(float4*)&As[srow * LDT + shalf * 16] = va0;
    *(float4*)&As[srow * LDT + shalf * 16 + 8] = va1;
    *(float4*)&Bs[srow * LDT + shalf * 16] = vb0;
    *(float4*)&Bs[srow * LDT + shalf * 16 + 8] = vb1;
    __syncthreads();
    int kc = lane >> 4, rl = lane & 15;
    bf16x8 af[4], bfv[4];
#pragma unroll
    for (int f = 0; f < 4; f++) {
      af[f] = *(const bf16x8*)&As[(wm * 64 + f * 16 + rl) * LDT + kc * 8];
      bfv[f] = *(const bf16x8*)&Bs[(wn * 64 + f * 16 + rl) * LDT + kc * 8];
    }
#pragma unroll
    for (int i = 0; i < 4; i++)
#pragma unroll
      for (int j = 0; j < 4; j++)
        acc[i][j] = __builtin_amdgcn_mfma_f32_16x16x32_bf16(af[i], bfv[j], acc[i][j], 0, 0, 0);
  }
  int cl = lane & 15, rg = lane >> 4;
#pragma unroll
  for (int i = 0; i < 4; i++) {
    int m = bm * 128 + wm * 64 + i * 16 + rg * 4;
#pragma unroll
    for (int j = 0; j < 4; j++) {
      int n = bn * 128 + wn * 64 + j * 16 + cl;
      float bv = bias[n];
#pragma unroll
      for (int r = 0; r < 4; r++)
        Cmat[(size_t)(m + r) * V + n] = acc[i][j][r] + bv;
    }
  }
}

// -------------------- in-place log_softmax (online stats, 4 indep accumulators) ----
__global__ __launch_bounds__(256) void k_logsoftmax(float* __restrict__ Cmat) {
  int row = blockIdx.x;
  float* p = Cmat + (size_t)row * V;
  int tid = threadIdx.x;
  __shared__ float sm[4], ss[4];
  float m0 = -1e30f, m1 = -1e30f, m2 = -1e30f, m3 = -1e30f;
  float s0 = 0.f, s1 = 0.f, s2 = 0.f, s3 = 0.f;
  for (int i = tid * 4; i < V; i += 1024) {
    float4 v = *(const float4*)&p[i];
    float n0 = fmaxf(m0, v.x); s0 = s0 * __expf(m0 - n0) + __expf(v.x - n0); m0 = n0;
    float n1 = fmaxf(m1, v.y); s1 = s1 * __expf(m1 - n1) + __expf(v.y - n1); m1 = n1;
    float n2 = fmaxf(m2, v.z); s2 = s2 * __expf(m2 - n2) + __expf(v.z - n2); m2 = n2;
    float n3 = fmaxf(m3, v.w); s3 = s3 * __expf(m3 - n3) + __expf(v.w - n3); m3 = n3;
  }
  float m = fmaxf(fmaxf(m0, m1), fmaxf(m2, m3));
  float s = s0 * __expf(m0 - m) + s1 * __expf(m1 - m)
          + s2 * __expf(m2 - m) + s3 * __expf(m3 - m);
  for (int o = 32; o; o >>= 1) {
    float om = __shfl_xor(m, o, 64), os = __shfl_xor(s, o, 64);
    float nm = fmaxf(m, om);
    s = s * __expf(m - nm) + os * __expf(om - nm);
    m = nm;
  }
  if ((tid & 63) == 0) { sm[tid >> 6] = m; ss[tid >> 6] = s; }
  __syncthreads();
  float M = fmaxf(fmaxf(sm[0], sm[1]), fmaxf(sm[2], sm[3]));
  float Ssum = ss[0] * __expf(sm[0] - M) + ss[1] * __expf(sm[1] - M)
             + ss[2] * __expf(sm[2] - M) + ss[3] * __expf(sm[3] - M);
  float lse = M + __logf(Ssum);
  for (int i = tid * 4; i < V; i += 1024) {
    float4 v = *(const float4*)&p[i];
    v.x -= lse; v.y -= lse; v.z -= lse; v.w -= lse;
    *(float4*)&p[i] = v;
  }
}

__global__ void k_copy_ht(const float* __restrict__ hsrc, float* __restrict__ o) {
  int i = blockIdx.x * 256 + threadIdx.x;
  if (i < B * H) o[i] = hsrc[i];
}

extern "C" void kernel_launch(void* const* d_in, const int* in_sizes, int n_in,
                              void* d_out, int out_size, void* d_ws, size_t ws_size,
                              hipStream_t stream) {
  (void)in_sizes; (void)n_in; (void)out_size; (void)ws_size;
  const float* keys = (const float*)d_in[0];
  const float* ehid = (const float*)d_in[1];
  const int* tgt    = (const int*)d_in[2];
  const float* emb  = (const float*)d_in[4];
  const float* Wa_w = (const float*)d_in[5];
  const float* Wa_b = (const float*)d_in[6];
  const float* Ua_w = (const float*)d_in[7];
  const float* Ua_b = (const float*)d_in[8];
  const float* Va_w = (const float*)d_in[9];
  const float* Va_b = (const float*)d_in[10];
  const float* W_ih = (const float*)d_in[11];
  const float* W_hh = (const float*)d_in[12];
  const float* b_ih = (const float*)d_in[13];
  const float* b_hh = (const float*)d_in[14];
  const float* out_w = (const float*)d_in[15];
  const float* out_b = (const float*)d_in[16];
  float* ws = (float*)d_ws;
  float* out = (float*)d_out;
  float* logits = out;                              // [B,T,V]
  float* ht_out = out + (size_t)B * T * V;          // [1,B,H]
  float* attn_out = ht_out + (size_t)B * H;         // [B,T,S]

  hipLaunchKernelGGL(k_init, dim3(64), dim3(256), 0, stream, ehid, tgt, ws);
  // Ua_keys = keys @ Ua_w.T + Ua_b -> [B*S][512]
  hipLaunchKernelGGL(k_gemm_at, dim3(32, 8), dim3(256), 0, stream,
                     keys, Ua_w, 512, Ua_b, ws + UAK_OFF, (const int*)nullptr, 512);
  // Gi_e = emb[tokens] @ W_ih[:, :512].T + b_ih -> [B*T][1536]
  hipLaunchKernelGGL(k_gemm_at, dim3(32, 24), dim3(256), 0, stream,
                     emb, W_ih, 1024, b_ih, ws + GIE_OFF, (const int*)(ws + ROWIDX_OFF), G3);
  // KWT f32 [b][col][s]
  hipLaunchKernelGGL(k_gemm_kwt, dim3(24, 32), dim3(256), 0, stream,
                     W_ih, keys, ws + KWT_OFF);
  // k-major packed f16x2 weights
  hipLaunchKernelGGL(k_pack_t, dim3(512), dim3(256), 0, stream,
                     Wa_w, (unsigned*)(ws + WA2T_OFF), 512);
  hipLaunchKernelGGL(k_pack_t, dim3(1536), dim3(256), 0, stream,
                     W_hh, (unsigned*)(ws + WHH2T_OFF), 1536);
  // persistent recurrence
  hipLaunchKernelGGL(k_recur, dim3(256), dim3(256), 0, stream,
                     Wa_b, Va_w, Va_b, b_hh,
                     (const unsigned*)(ws + WA2T_OFF), (const unsigned*)(ws + WHH2T_OFF),
                     ws, attn_out);
  hipLaunchKernelGGL(k_copy_ht, dim3(64), dim3(256), 0, stream,
                     ws + HALL_OFF + (size_t)T * B * H, ht_out);
  // bf16 out_w copy into the (now dead) precompute region
  hipLaunchKernelGGL(k_conv_outw, dim3((V * H / 4 + 255) / 256), dim3(256), 0, stream,
                     out_w, (ushort*)(ws + OWBF_OFF), V * H / 4);
  hipLaunchKernelGGL(k_outgemm, dim3(250, 16), dim3(256), 0, stream,
                     (const __hip_bfloat16*)(ws + HBF_OFF),
                     (const __hip_bfloat16*)(ws + OWBF_OFF), out_b, logits);
  hipLaunchKernelGGL(k_logsoftmax, dim3(BT), dim3(256), 0, stream, logits);
}